// Round 2
// baseline (1205.794 us; speedup 1.0000x reference)
//
#include <hip/hip_runtime.h>

#define N_NODES 50000
#define N_EDGES 600000
#define C 128

typedef __bf16 bf16;
typedef __attribute__((ext_vector_type(8))) __bf16 bf16x8;
typedef __attribute__((ext_vector_type(4))) __bf16 bf16x4;
typedef __attribute__((ext_vector_type(4))) float f32x4;

struct PtrsV { const void* p[8]; };

// ---------------------------------------------------------------------------
// Dtype detection: "wild-as-bf16" = NaN/Inf, |x|>=64, denormal, or 0<|x|<2^-12.
// fp32 data read as bf16 -> ~47% of halfwords wild. Real bf16 ~N(0,1) or
// uniform(+-0.09) data -> ~0% wild. Flags: 1 = fp32, 0 = bf16.
// ---------------------------------------------------------------------------
__device__ __forceinline__ int bf16_wild(unsigned short w) {
    int exp = (w >> 7) & 0xFF;
    int mant = w & 0x7F;
    if (exp == 0xFF) return 1;
    if (exp >= 133) return 1;                // |x| >= 64
    if (exp == 0) return mant != 0 ? 1 : 0;  // denormal
    if (exp <= 114) return 1;                // 0 < |x| < 2^-12
    return 0;
}

__global__ void __launch_bounds__(64) detect_kernel(
    const unsigned short* __restrict__ emb,
    const unsigned short* __restrict__ w,
    const unsigned short* __restrict__ b,
    const unsigned short* __restrict__ hc,
    int* __restrict__ flags)
{
    int lane = threadIdx.x;  // 64 lanes
    int ce = 0, cw = 0, cb = 0, ch = 0;
    for (int j = 0; j < 4; ++j) {
        ce += bf16_wild(emb[lane * 4 + j]);
        cw += bf16_wild(w[lane * 4 + j]);
    }
    for (int j = 0; j < 2; ++j) cb += bf16_wild(b[lane * 2 + j]);
    if (lane < 3) ch = bf16_wild(hc[lane]);   // only 3 halfwords are safe to read
    for (int off = 32; off > 0; off >>= 1) {
        ce += __shfl_down(ce, off);
        cw += __shfl_down(cw, off);
        cb += __shfl_down(cb, off);
        ch += __shfl_down(ch, off);
    }
    if (lane == 0) {
        int wf = (cw >= 16) ? 1 : 0;
        flags[0] = (ce >= 16) ? 1 : 0;           // emb (also governs output dtype)
        flags[1] = wf;                           // weight matrices
        flags[2] = (cb >= 8) ? 1 : 0;            // biases
        flags[3] = (ch > 0) ? 1 : wf;            // hop_coef: tiny scan, fallback = weight flag
    }
}

// ---------------------------------------------------------------------------
// Pack 8 weight matrices [128x128] row-major W[k][n] into MFMA B-fragment
// order; also build canonical fp32 biases [8][128] and hop_coef [3].
// packed element tid: m(3b) | kk(2b) | n0(3b) | lane(6b) | j(3b)
//   k = kk*32 + (lane>>4)*8 + j ; n = n0*16 + (lane&15)
// Matrix slots 4,5 (and bias slots 4,5) are the SECOND hh matrix: the base
// pointer is the hh stack, so add one matrix (16384 elems) / one bias (128).
// ---------------------------------------------------------------------------
__global__ void __launch_bounds__(256) pack_kernel(
    PtrsV wmats, PtrsV bvecs, const void* hc_raw,
    const int* __restrict__ flags,
    bf16* __restrict__ pw, float* __restrict__ cbias, float* __restrict__ ccoef)
{
    int tid = blockIdx.x * 256 + threadIdx.x;
    int wf = flags[1], bfl = flags[2], hf = flags[3];
    if (tid < 8 * 16384) {
        int m    = tid >> 14;
        int r    = tid & 16383;
        int j    = r & 7;
        int lane = (r >> 3) & 63;
        int n0   = (r >> 9) & 7;
        int kk   = r >> 12;
        int k = kk * 32 + (lane >> 4) * 8 + j;
        int n = n0 * 16 + (lane & 15);
        int idx = k * C + n + ((m == 4 || m == 5) ? 16384 : 0);
        float v = wf ? ((const float*)wmats.p[m])[idx]
                     : (float)((const bf16*)wmats.p[m])[idx];
        pw[tid] = (bf16)v;
    } else if (tid < 8 * 16384 + 1024) {
        int j = tid - 8 * 16384;
        int m = j >> 7, n = j & 127;
        int idx = n + ((m == 4 || m == 5) ? 128 : 0);
        float v = bfl ? ((const float*)bvecs.p[m])[idx]
                      : (float)((const bf16*)bvecs.p[m])[idx];
        cbias[j] = v;
    } else if (tid < 8 * 16384 + 1024 + 3) {
        int i = tid - (8 * 16384 + 1024);
        float v = hf ? ((const float*)hc_raw)[i]
                     : (float)((const bf16*)hc_raw)[i];
        ccoef[i] = v;
    }
}

// ---------------------------------------------------------------------------
// Fused MLP kernel: grid.y = which MLP (0=rel on emb[2], 1=hh0 on emb[1],
// 2=hh1 on emb[0], 3=loop(self) on emb[2]).  Block = 256 threads = 4 waves,
// each block computes 64 nodes x 128 ch of relu(X@W1+b1)@W2+b2.
// my<3 -> bf16 h[my];  my==3 -> fp32 accumulator (self term).
// ---------------------------------------------------------------------------
__global__ void __launch_bounds__(256) mlp_all_kernel(
    const void* __restrict__ emb_raw,    // [3][N][C] fp32 or bf16
    const bf16* __restrict__ pw,         // packed weights [8][16384]
    const float* __restrict__ cbias,     // [8][128]
    const int* __restrict__ flags,
    bf16* __restrict__ h,                // [3][N][C]
    float* __restrict__ acc)             // [N][C]
{
    __shared__ bf16 sX[64][136];   // stride 272 B (16B multiple, breaks 128-stride)
    __shared__ bf16 sH[64][136];

    const int my    = blockIdx.y;
    const int node0 = blockIdx.x * 64;
    const int tid   = threadIdx.x;
    const int emb_f32 = flags[0];

    const int layer_idx[4] = {2, 1, 0, 2};
    const size_t xoff = (size_t)layer_idx[my] * N_NODES * C;

    // ---- stage X tile (64 nodes x 128 ch) into LDS as bf16 ----
    {
        int rr = tid >> 4;           // 0..15
        int cc = (tid & 15) * 8;     // 0..120
        for (int p2 = 0; p2 < 4; ++p2) {
            int m = rr + p2 * 16;
            int node = node0 + m;
            bf16x8 v;
            if (node < N_NODES) {
                size_t o = xoff + (size_t)node * C + cc;
                if (emb_f32) {
                    const float* xf = (const float*)emb_raw + o;
                    f32x4 u0 = *(const f32x4*)(xf);
                    f32x4 u1 = *(const f32x4*)(xf + 4);
                    v[0] = (bf16)u0[0]; v[1] = (bf16)u0[1]; v[2] = (bf16)u0[2]; v[3] = (bf16)u0[3];
                    v[4] = (bf16)u1[0]; v[5] = (bf16)u1[1]; v[6] = (bf16)u1[2]; v[7] = (bf16)u1[3];
                } else {
                    v = *(const bf16x8*)((const bf16*)emb_raw + o);
                }
            } else {
                for (int j = 0; j < 8; ++j) v[j] = (bf16)0.0f;
            }
            *(bf16x8*)(&sX[m][cc]) = v;
        }
    }
    __syncthreads();

    const int lane  = tid & 63;
    const int wave  = tid >> 6;
    const int m0    = wave * 16;
    const int lrow  = lane & 15;
    const int lquad = lane >> 4;

    const bf16* w1 = pw + (size_t)(my * 2) * 16384;
    const bf16* w2 = w1 + 16384;

    // ---- GEMM 1: hidden = relu(X @ W1 + b1) ----
    f32x4 acc1[8];
    for (int i = 0; i < 8; ++i) { acc1[i][0]=0.f; acc1[i][1]=0.f; acc1[i][2]=0.f; acc1[i][3]=0.f; }
    #pragma unroll
    for (int kk = 0; kk < 4; ++kk) {
        bf16x8 a = *(const bf16x8*)(&sX[m0 + lrow][kk * 32 + lquad * 8]);
        const bf16x8* bfr = (const bf16x8*)w1 + (size_t)kk * 512 + lane;
        #pragma unroll
        for (int n0 = 0; n0 < 8; ++n0) {
            bf16x8 b = bfr[(size_t)n0 * 64];
            acc1[n0] = __builtin_amdgcn_mfma_f32_16x16x32_bf16(a, b, acc1[n0], 0, 0, 0);
        }
    }
    const float* b1 = cbias + my * 2 * 128;
    #pragma unroll
    for (int n0 = 0; n0 < 8; ++n0) {
        int n = n0 * 16 + lrow;
        float bias = b1[n];
        #pragma unroll
        for (int r = 0; r < 4; ++r) {
            float v = acc1[n0][r] + bias;
            v = v > 0.f ? v : 0.f;
            sH[m0 + lquad * 4 + r][n] = (bf16)v;
        }
    }
    // In-wave LDS dependency only (each wave reads exactly the 16 rows its own
    // lanes wrote); compiler inserts lgkmcnt — no __syncthreads needed.

    // ---- GEMM 2: out = hidden @ W2 + b2 ----
    f32x4 acc2[8];
    for (int i = 0; i < 8; ++i) { acc2[i][0]=0.f; acc2[i][1]=0.f; acc2[i][2]=0.f; acc2[i][3]=0.f; }
    #pragma unroll
    for (int kk = 0; kk < 4; ++kk) {
        bf16x8 a = *(const bf16x8*)(&sH[m0 + lrow][kk * 32 + lquad * 8]);
        const bf16x8* bfr = (const bf16x8*)w2 + (size_t)kk * 512 + lane;
        #pragma unroll
        for (int n0 = 0; n0 < 8; ++n0) {
            bf16x8 b = bfr[(size_t)n0 * 64];
            acc2[n0] = __builtin_amdgcn_mfma_f32_16x16x32_bf16(a, b, acc2[n0], 0, 0, 0);
        }
    }
    const float* b2 = cbias + (my * 2 + 1) * 128;
    if (my < 3) {
        bf16* ho = h + (size_t)my * N_NODES * C;
        #pragma unroll
        for (int n0 = 0; n0 < 8; ++n0) {
            int n = n0 * 16 + lrow;
            float bias = b2[n];
            #pragma unroll
            for (int r = 0; r < 4; ++r) {
                int node = node0 + m0 + lquad * 4 + r;
                if (node < N_NODES)
                    ho[(size_t)node * C + n] = (bf16)(acc2[n0][r] + bias);
            }
        }
    } else {
        #pragma unroll
        for (int n0 = 0; n0 < 8; ++n0) {
            int n = n0 * 16 + lrow;
            float bias = b2[n];
            #pragma unroll
            for (int r = 0; r < 4; ++r) {
                int node = node0 + m0 + lquad * 4 + r;
                if (node < N_NODES)
                    acc[(size_t)node * C + n] = acc2[n0][r] + bias;
            }
        }
    }
}

// ---------------------------------------------------------------------------
// Scatter: acc[row[e]] += coef[w-1] * h_{w}[col[e]]   (w = ew[e] in 1..3)
// 32 lanes per edge, 4 channels each (bf16x4 gather, 4 fp32 atomics).
// ---------------------------------------------------------------------------
__global__ void __launch_bounds__(256) scatter_kernel(
    const int* __restrict__ erow, const int* __restrict__ ecol,
    const int* __restrict__ ew,
    const bf16* __restrict__ h,          // [3][N][C]
    const float* __restrict__ ccoef,     // [3]
    float* __restrict__ acc)             // [N][C]
{
    int t = blockIdx.x * 256 + threadIdx.x;
    int e = t >> 5;
    if (e >= N_EDGES) return;
    int c0 = (t & 31) * 4;
    int w   = ew[e];        // 1..3
    int dst = erow[e];
    int src = ecol[e];
    float coef = ccoef[w - 1];
    const bf16* hsrc = h + (size_t)(w - 1) * N_NODES * C + (size_t)src * C + c0;
    bf16x4 v = *(const bf16x4*)hsrc;
    float* a = acc + (size_t)dst * C + c0;
    atomicAdd(a + 0, coef * (float)v[0]);
    atomicAdd(a + 1, coef * (float)v[1]);
    atomicAdd(a + 2, coef * (float)v[2]);
    atomicAdd(a + 3, coef * (float)v[3]);
}

// ---------------------------------------------------------------------------
// Finalize: out = acc, as fp32 or bf16 per detected output dtype (= emb dtype)
// ---------------------------------------------------------------------------
__global__ void __launch_bounds__(256) finalize_kernel(
    const float* __restrict__ acc, void* __restrict__ out,
    const int* __restrict__ flags)
{
    int i = blockIdx.x * 256 + threadIdx.x;   // one 4-elem group per thread
    f32x4 v = ((const f32x4*)acc)[i];
    if (flags[0]) {
        ((f32x4*)out)[i] = v;
    } else {
        bf16x4 o;
        o[0] = (bf16)v[0]; o[1] = (bf16)v[1]; o[2] = (bf16)v[2]; o[3] = (bf16)v[3];
        ((bf16x4*)out)[i] = o;
    }
}

// ---------------------------------------------------------------------------
extern "C" void kernel_launch(void* const* d_in, const int* in_sizes, int n_in,
                              void* d_out, int out_size, void* d_ws, size_t ws_size,
                              hipStream_t stream) {
    // 0 t | 1 node_embeddings [3,N,C] | 2 edge_index [2,E] | 3 edge_weights [E]
    // 4 loop_W1 5 loop_b1 6 loop_W2 7 loop_b2 | 8 rel_W1 9 rel_b1 10 rel_W2 11 rel_b2
    // 12 hh_W1 [2,C,C] 13 hh_b1 [2,C] 14 hh_W2 [2,C,C] 15 hh_b2 [2,C] | 16 hop_coef [3]
    const void* emb = d_in[1];
    const int*  ei  = (const int*)d_in[2];
    const int*  ew  = (const int*)d_in[3];

    // ws: acc f32[N*C] | h bf16[3*N*C] | pw bf16[8*16384] | cbias f32[1024] | ccoef f32[4] | flags int[16]
    const size_t ACC_BYTES = (size_t)N_NODES * C * sizeof(float);        // 25.6 MB
    const size_t H_BYTES   = (size_t)3 * N_NODES * C * sizeof(bf16);     // 38.4 MB
    const size_t PW_BYTES  = (size_t)8 * 16384 * sizeof(bf16);           // 256 KB
    float* acc   = (float*)d_ws;
    bf16*  h     = (bf16*)((char*)d_ws + ACC_BYTES);
    bf16*  pw    = (bf16*)((char*)d_ws + ACC_BYTES + H_BYTES);
    float* cbias = (float*)((char*)d_ws + ACC_BYTES + H_BYTES + PW_BYTES);
    float* ccoef = cbias + 1024;
    int*   flags = (int*)(ccoef + 4);

    // MLP id -> matrices: 0:rel  1:hh[0]  2:hh[1]  3:loop
    PtrsV wptr;
    wptr.p[0] = d_in[8];   // rel_W1
    wptr.p[1] = d_in[10];  // rel_W2
    wptr.p[2] = d_in[12];  // hh_W1[0]
    wptr.p[3] = d_in[14];  // hh_W2[0]
    wptr.p[4] = d_in[12];  // hh_W1[1]  (pack adds +16384 elems for m==4/5)
    wptr.p[5] = d_in[14];  // hh_W2[1]
    wptr.p[6] = d_in[4];   // loop_W1
    wptr.p[7] = d_in[6];   // loop_W2
    PtrsV bptr;
    bptr.p[0] = d_in[9];   // rel_b1
    bptr.p[1] = d_in[11];  // rel_b2
    bptr.p[2] = d_in[13];  // hh_b1[0]
    bptr.p[3] = d_in[15];  // hh_b2[0]
    bptr.p[4] = d_in[13];  // hh_b1[1]  (pack adds +128 for m==4/5)
    bptr.p[5] = d_in[15];  // hh_b2[1]
    bptr.p[6] = d_in[5];   // loop_b1
    bptr.p[7] = d_in[7];   // loop_b2

    detect_kernel<<<1, 64, 0, stream>>>(
        (const unsigned short*)emb, (const unsigned short*)d_in[8],
        (const unsigned short*)d_in[9], (const unsigned short*)d_in[16], flags);

    pack_kernel<<<517, 256, 0, stream>>>(wptr, bptr, d_in[16], flags, pw, cbias, ccoef);

    dim3 grid_mlp((N_NODES + 63) / 64, 4);
    mlp_all_kernel<<<grid_mlp, 256, 0, stream>>>(emb, pw, cbias, flags, h, acc);

    const int* erow = ei;
    const int* ecol = ei + N_EDGES;
    scatter_kernel<<<(N_EDGES * 32) / 256, 256, 0, stream>>>(erow, ecol, ew, h, ccoef, acc);

    finalize_kernel<<<(N_NODES * C / 4 + 255) / 256, 256, 0, stream>>>(acc, d_out, flags);
}

// Round 3
// 355.440 us; speedup vs baseline: 3.3924x; 3.3924x over previous
//
#include <hip/hip_runtime.h>

#define N_NODES 50000
#define N_EDGES 600000
#define C 128

typedef __bf16 bf16;
typedef __attribute__((ext_vector_type(8))) __bf16 bf16x8;
typedef __attribute__((ext_vector_type(4))) __bf16 bf16x4;
typedef __attribute__((ext_vector_type(2))) __bf16 bf16x2;
typedef __attribute__((ext_vector_type(4))) float f32x4;
typedef __attribute__((ext_vector_type(2))) float f32x2;

struct PtrsV { const void* p[8]; };

// ---------------------------------------------------------------------------
// Dtype detection: "wild-as-bf16" = NaN/Inf, |x|>=64, denormal, or 0<|x|<2^-12.
// fp32 data read as bf16 -> ~47% of halfwords wild. Real bf16 ~N(0,1) or
// uniform(+-0.09) data -> ~0% wild. Flags: 1 = fp32, 0 = bf16.
// ---------------------------------------------------------------------------
__device__ __forceinline__ int bf16_wild(unsigned short w) {
    int exp = (w >> 7) & 0xFF;
    int mant = w & 0x7F;
    if (exp == 0xFF) return 1;
    if (exp >= 133) return 1;                // |x| >= 64
    if (exp == 0) return mant != 0 ? 1 : 0;  // denormal
    if (exp <= 114) return 1;                // 0 < |x| < 2^-12
    return 0;
}

__global__ void __launch_bounds__(64) detect_kernel(
    const unsigned short* __restrict__ emb,
    const unsigned short* __restrict__ w,
    const unsigned short* __restrict__ b,
    const unsigned short* __restrict__ hc,
    int* __restrict__ flags)
{
    int lane = threadIdx.x;  // 64 lanes
    int ce = 0, cw = 0, cb = 0, ch = 0;
    for (int j = 0; j < 4; ++j) {
        ce += bf16_wild(emb[lane * 4 + j]);
        cw += bf16_wild(w[lane * 4 + j]);
    }
    for (int j = 0; j < 2; ++j) cb += bf16_wild(b[lane * 2 + j]);
    if (lane < 3) ch = bf16_wild(hc[lane]);   // only 3 halfwords are safe to read
    for (int off = 32; off > 0; off >>= 1) {
        ce += __shfl_down(ce, off);
        cw += __shfl_down(cw, off);
        cb += __shfl_down(cb, off);
        ch += __shfl_down(ch, off);
    }
    if (lane == 0) {
        int wf = (cw >= 16) ? 1 : 0;
        flags[0] = (ce >= 16) ? 1 : 0;           // emb (also governs output dtype)
        flags[1] = wf;                           // weight matrices
        flags[2] = (cb >= 8) ? 1 : 0;            // biases
        flags[3] = (ch > 0) ? 1 : wf;            // hop_coef: tiny scan, fallback = weight flag
    }
}

// ---------------------------------------------------------------------------
// Pack 8 weight matrices [128x128] row-major W[k][n] into MFMA B-fragment
// order; also build canonical fp32 biases [8][128] and hop_coef [3].
// Matrix slots 4,5 (and bias slots 4,5) are the SECOND hh matrix: base
// pointer is the hh stack, so add one matrix (16384 elems) / one bias (128).
// ---------------------------------------------------------------------------
__global__ void __launch_bounds__(256) pack_kernel(
    PtrsV wmats, PtrsV bvecs, const void* hc_raw,
    const int* __restrict__ flags,
    bf16* __restrict__ pw, float* __restrict__ cbias, float* __restrict__ ccoef)
{
    int tid = blockIdx.x * 256 + threadIdx.x;
    int wf = flags[1], bfl = flags[2], hf = flags[3];
    if (tid < 8 * 16384) {
        int m    = tid >> 14;
        int r    = tid & 16383;
        int j    = r & 7;
        int lane = (r >> 3) & 63;
        int n0   = (r >> 9) & 7;
        int kk   = r >> 12;
        int k = kk * 32 + (lane >> 4) * 8 + j;
        int n = n0 * 16 + (lane & 15);
        int idx = k * C + n + ((m == 4 || m == 5) ? 16384 : 0);
        float v = wf ? ((const float*)wmats.p[m])[idx]
                     : (float)((const bf16*)wmats.p[m])[idx];
        pw[tid] = (bf16)v;
    } else if (tid < 8 * 16384 + 1024) {
        int j = tid - 8 * 16384;
        int m = j >> 7, n = j & 127;
        int idx = n + ((m == 4 || m == 5) ? 128 : 0);
        float v = bfl ? ((const float*)bvecs.p[m])[idx]
                      : (float)((const bf16*)bvecs.p[m])[idx];
        cbias[j] = v;
    } else if (tid < 8 * 16384 + 1024 + 3) {
        int i = tid - (8 * 16384 + 1024);
        float v = hf ? ((const float*)hc_raw)[i]
                     : (float)((const bf16*)hc_raw)[i];
        ccoef[i] = v;
    }
}

// ---------------------------------------------------------------------------
// Fused MLP kernel: grid.y = which MLP (0=rel on emb[2], 1=hh0 on emb[1],
// 2=hh1 on emb[0], 3=loop(self) on emb[2]).  Block = 256 threads = 4 waves,
// each block computes 64 nodes x 128 ch of relu(X@W1+b1)@W2+b2.
// my<3 -> bf16 h[my];  my==3 -> fp32 accumulator (self term).
// ---------------------------------------------------------------------------
__global__ void __launch_bounds__(256) mlp_all_kernel(
    const void* __restrict__ emb_raw,    // [3][N][C] fp32 or bf16
    const bf16* __restrict__ pw,         // packed weights [8][16384]
    const float* __restrict__ cbias,     // [8][128]
    const int* __restrict__ flags,
    bf16* __restrict__ h,                // [3][N][C]
    float* __restrict__ acc)             // [N][C]
{
    __shared__ bf16 sX[64][136];   // stride 272 B (16B multiple, breaks 128-stride)
    __shared__ bf16 sH[64][136];

    const int my    = blockIdx.y;
    const int node0 = blockIdx.x * 64;
    const int tid   = threadIdx.x;
    const int emb_f32 = flags[0];

    const int layer_idx[4] = {2, 1, 0, 2};
    const size_t xoff = (size_t)layer_idx[my] * N_NODES * C;

    // ---- stage X tile (64 nodes x 128 ch) into LDS as bf16 ----
    {
        int rr = tid >> 4;           // 0..15
        int cc = (tid & 15) * 8;     // 0..120
        for (int p2 = 0; p2 < 4; ++p2) {
            int m = rr + p2 * 16;
            int node = node0 + m;
            bf16x8 v;
            if (node < N_NODES) {
                size_t o = xoff + (size_t)node * C + cc;
                if (emb_f32) {
                    const float* xf = (const float*)emb_raw + o;
                    f32x4 u0 = *(const f32x4*)(xf);
                    f32x4 u1 = *(const f32x4*)(xf + 4);
                    v[0] = (bf16)u0[0]; v[1] = (bf16)u0[1]; v[2] = (bf16)u0[2]; v[3] = (bf16)u0[3];
                    v[4] = (bf16)u1[0]; v[5] = (bf16)u1[1]; v[6] = (bf16)u1[2]; v[7] = (bf16)u1[3];
                } else {
                    v = *(const bf16x8*)((const bf16*)emb_raw + o);
                }
            } else {
                for (int j = 0; j < 8; ++j) v[j] = (bf16)0.0f;
            }
            *(bf16x8*)(&sX[m][cc]) = v;
        }
    }
    __syncthreads();

    const int lane  = tid & 63;
    const int wave  = tid >> 6;
    const int m0    = wave * 16;
    const int lrow  = lane & 15;
    const int lquad = lane >> 4;

    const bf16* w1 = pw + (size_t)(my * 2) * 16384;
    const bf16* w2 = w1 + 16384;

    // ---- GEMM 1: hidden = relu(X @ W1 + b1) ----
    f32x4 acc1[8];
    for (int i = 0; i < 8; ++i) { acc1[i][0]=0.f; acc1[i][1]=0.f; acc1[i][2]=0.f; acc1[i][3]=0.f; }
    #pragma unroll
    for (int kk = 0; kk < 4; ++kk) {
        bf16x8 a = *(const bf16x8*)(&sX[m0 + lrow][kk * 32 + lquad * 8]);
        const bf16x8* bfr = (const bf16x8*)w1 + (size_t)kk * 512 + lane;
        #pragma unroll
        for (int n0 = 0; n0 < 8; ++n0) {
            bf16x8 b = bfr[(size_t)n0 * 64];
            acc1[n0] = __builtin_amdgcn_mfma_f32_16x16x32_bf16(a, b, acc1[n0], 0, 0, 0);
        }
    }
    const float* b1 = cbias + my * 2 * 128;
    #pragma unroll
    for (int n0 = 0; n0 < 8; ++n0) {
        int n = n0 * 16 + lrow;
        float bias = b1[n];
        #pragma unroll
        for (int r = 0; r < 4; ++r) {
            float v = acc1[n0][r] + bias;
            v = v > 0.f ? v : 0.f;
            sH[m0 + lquad * 4 + r][n] = (bf16)v;
        }
    }
    // In-wave LDS dependency only — no __syncthreads needed.

    // ---- GEMM 2: out = hidden @ W2 + b2 ----
    f32x4 acc2[8];
    for (int i = 0; i < 8; ++i) { acc2[i][0]=0.f; acc2[i][1]=0.f; acc2[i][2]=0.f; acc2[i][3]=0.f; }
    #pragma unroll
    for (int kk = 0; kk < 4; ++kk) {
        bf16x8 a = *(const bf16x8*)(&sH[m0 + lrow][kk * 32 + lquad * 8]);
        const bf16x8* bfr = (const bf16x8*)w2 + (size_t)kk * 512 + lane;
        #pragma unroll
        for (int n0 = 0; n0 < 8; ++n0) {
            bf16x8 b = bfr[(size_t)n0 * 64];
            acc2[n0] = __builtin_amdgcn_mfma_f32_16x16x32_bf16(a, b, acc2[n0], 0, 0, 0);
        }
    }
    const float* b2 = cbias + (my * 2 + 1) * 128;
    if (my < 3) {
        bf16* ho = h + (size_t)my * N_NODES * C;
        #pragma unroll
        for (int n0 = 0; n0 < 8; ++n0) {
            int n = n0 * 16 + lrow;
            float bias = b2[n];
            #pragma unroll
            for (int r = 0; r < 4; ++r) {
                int node = node0 + m0 + lquad * 4 + r;
                if (node < N_NODES)
                    ho[(size_t)node * C + n] = (bf16)(acc2[n0][r] + bias);
            }
        }
    } else {
        #pragma unroll
        for (int n0 = 0; n0 < 8; ++n0) {
            int n = n0 * 16 + lrow;
            float bias = b2[n];
            #pragma unroll
            for (int r = 0; r < 4; ++r) {
                int node = node0 + m0 + lquad * 4 + r;
                if (node < N_NODES)
                    acc[(size_t)node * C + n] = acc2[n0][r] + bias;
            }
        }
    }
}

// ---------------------------------------------------------------------------
// CSR build step 1: histogram of destination degrees.
// ---------------------------------------------------------------------------
__global__ void __launch_bounds__(256) hist_kernel(
    const int* __restrict__ erow, int* __restrict__ deg)
{
    int e = blockIdx.x * 256 + threadIdx.x;
    if (e >= N_EDGES) return;
    atomicAdd(&deg[erow[e]], 1);
}

// ---------------------------------------------------------------------------
// CSR build step 2: exclusive prefix sum over 50000 degrees (single block,
// 1024 threads, shuffle-based wave scans — ~49 chunks x 4 barriers).
// Writes offsets[0..N] and cursor[0..N-1] (= offsets copy for the fill).
// ---------------------------------------------------------------------------
__global__ void __launch_bounds__(1024) scan_kernel(
    const int* __restrict__ deg, int* __restrict__ offsets, int* __restrict__ cursor)
{
    __shared__ int swave[16];
    __shared__ int s_running;
    __shared__ int s_chunk_total;
    const int tid = threadIdx.x, lane = tid & 63, wv = tid >> 6;
    if (tid == 0) s_running = 0;
    __syncthreads();
    for (int base = 0; base < N_NODES; base += 1024) {
        int i = base + tid;
        int v = (i < N_NODES) ? deg[i] : 0;
        // wave-level inclusive scan
        int x = v;
        #pragma unroll
        for (int d = 1; d < 64; d <<= 1) {
            int t = __shfl_up(x, d);
            if (lane >= d) x += t;
        }
        if (lane == 63) swave[wv] = x;
        __syncthreads();
        if (wv == 0) {
            int wt = (lane < 16) ? swave[lane] : 0;
            #pragma unroll
            for (int d = 1; d < 16; d <<= 1) {
                int t = __shfl_up(wt, d);
                if (lane >= d) wt += t;
            }
            if (lane < 16) swave[lane] = wt;
            if (lane == 15) s_chunk_total = wt;
        }
        __syncthreads();
        int wave_prefix = (wv > 0) ? swave[wv - 1] : 0;
        int run = s_running;
        int excl = run + wave_prefix + x - v;
        if (i < N_NODES) { offsets[i] = excl; cursor[i] = excl; }
        __syncthreads();
        if (tid == 0) s_running = run + s_chunk_total;
        __syncthreads();
    }
    if (tid == 0) offsets[N_NODES] = s_running;
}

// ---------------------------------------------------------------------------
// CSR build step 3: bucket-fill. edge_data[pos] = src*4 + (hop-1).
// ---------------------------------------------------------------------------
__global__ void __launch_bounds__(256) fill_kernel(
    const int* __restrict__ erow, const int* __restrict__ ecol,
    const int* __restrict__ ew,
    int* __restrict__ cursor, int* __restrict__ edata)
{
    int e = blockIdx.x * 256 + threadIdx.x;
    if (e >= N_EDGES) return;
    int dst = erow[e];
    int pos = atomicAdd(&cursor[dst], 1);
    edata[pos] = (ecol[e] << 2) | (ew[e] - 1);
}

// ---------------------------------------------------------------------------
// Gather: one wave per destination node, lane = 2 channels (bf16x2).
// out[node] = acc_self[node] + sum_e coef[hop_e] * h[hop_e][src_e].
// No atomics; fuses the finalize (writes final output in detected dtype).
// ---------------------------------------------------------------------------
__global__ void __launch_bounds__(256) gather_kernel(
    const int* __restrict__ offsets, const int* __restrict__ edata,
    const bf16* __restrict__ h,          // [3][N][C]
    const float* __restrict__ ccoef,     // [3]
    const float* __restrict__ acc,       // [N][C] self term
    void* __restrict__ out,
    const int* __restrict__ flags)
{
    const int node = blockIdx.x * 4 + (threadIdx.x >> 6);
    if (node >= N_NODES) return;
    const int lane = threadIdx.x & 63;
    const int c = lane * 2;

    const float cf0 = ccoef[0], cf1 = ccoef[1], cf2 = ccoef[2];
    f32x2 a = *(const f32x2*)(acc + (size_t)node * C + c);

    const int s = offsets[node], e = offsets[node + 1];
    for (int base = s; base < e; base += 64) {
        int ed_i = (base + lane < e) ? edata[base + lane] : 0;
        int cnt = e - base; if (cnt > 64) cnt = 64;
        for (int j = 0; j < cnt; ++j) {
            int ed  = __shfl(ed_i, j);
            int hop = ed & 3;
            int src = ed >> 2;
            float cf = (hop == 0) ? cf0 : ((hop == 1) ? cf1 : cf2);
            bf16x2 v = *(const bf16x2*)(h + (size_t)hop * N_NODES * C + (size_t)src * C + c);
            a[0] += cf * (float)v[0];
            a[1] += cf * (float)v[1];
        }
    }

    if (flags[0]) {
        *(f32x2*)((float*)out + (size_t)node * C + c) = a;
    } else {
        bf16x2 o; o[0] = (bf16)a[0]; o[1] = (bf16)a[1];
        *(bf16x2*)((bf16*)out + (size_t)node * C + c) = o;
    }
}

// ---------------------------------------------------------------------------
extern "C" void kernel_launch(void* const* d_in, const int* in_sizes, int n_in,
                              void* d_out, int out_size, void* d_ws, size_t ws_size,
                              hipStream_t stream) {
    // 0 t | 1 node_embeddings [3,N,C] | 2 edge_index [2,E] | 3 edge_weights [E]
    // 4 loop_W1 5 loop_b1 6 loop_W2 7 loop_b2 | 8 rel_W1 9 rel_b1 10 rel_W2 11 rel_b2
    // 12 hh_W1 [2,C,C] 13 hh_b1 [2,C] 14 hh_W2 [2,C,C] 15 hh_b2 [2,C] | 16 hop_coef [3]
    const void* emb = d_in[1];
    const int*  ei  = (const int*)d_in[2];
    const int*  ew  = (const int*)d_in[3];

    // ws: acc f32[N*C] | h bf16[3*N*C] | pw bf16[8*16384] | cbias f32[1024] |
    //     ccoef f32[4] | flags int[16] | deg int[N] | cursor int[N] |
    //     offsets int[N+8] | edata int[E]
    const size_t ACC_BYTES = (size_t)N_NODES * C * sizeof(float);        // 25.6 MB
    const size_t H_BYTES   = (size_t)3 * N_NODES * C * sizeof(bf16);     // 38.4 MB
    const size_t PW_BYTES  = (size_t)8 * 16384 * sizeof(bf16);           // 256 KB
    float* acc    = (float*)d_ws;
    bf16*  h      = (bf16*)((char*)d_ws + ACC_BYTES);
    bf16*  pw     = (bf16*)((char*)d_ws + ACC_BYTES + H_BYTES);
    float* cbias  = (float*)((char*)d_ws + ACC_BYTES + H_BYTES + PW_BYTES);
    float* ccoef  = cbias + 1024;
    int*   flags  = (int*)(ccoef + 4);
    int*   deg    = flags + 16;
    int*   cursor = deg + N_NODES;
    int*   offsets= cursor + N_NODES;
    int*   edata  = offsets + N_NODES + 8;

    // MLP id -> matrices: 0:rel  1:hh[0]  2:hh[1]  3:loop
    PtrsV wptr;
    wptr.p[0] = d_in[8];   wptr.p[1] = d_in[10];
    wptr.p[2] = d_in[12];  wptr.p[3] = d_in[14];
    wptr.p[4] = d_in[12];  wptr.p[5] = d_in[14];   // +16384 elems inside pack
    wptr.p[6] = d_in[4];   wptr.p[7] = d_in[6];
    PtrsV bptr;
    bptr.p[0] = d_in[9];   bptr.p[1] = d_in[11];
    bptr.p[2] = d_in[13];  bptr.p[3] = d_in[15];
    bptr.p[4] = d_in[13];  bptr.p[5] = d_in[15];   // +128 inside pack
    bptr.p[6] = d_in[5];   bptr.p[7] = d_in[7];

    detect_kernel<<<1, 64, 0, stream>>>(
        (const unsigned short*)emb, (const unsigned short*)d_in[8],
        (const unsigned short*)d_in[9], (const unsigned short*)d_in[16], flags);

    pack_kernel<<<517, 256, 0, stream>>>(wptr, bptr, d_in[16], flags, pw, cbias, ccoef);

    // CSR build (independent of MLP output; stream-ordered before gather)
    hipMemsetAsync(deg, 0, N_NODES * sizeof(int), stream);
    const int* erow = ei;
    const int* ecol = ei + N_EDGES;
    hist_kernel<<<(N_EDGES + 255) / 256, 256, 0, stream>>>(erow, deg);
    scan_kernel<<<1, 1024, 0, stream>>>(deg, offsets, cursor);
    fill_kernel<<<(N_EDGES + 255) / 256, 256, 0, stream>>>(erow, ecol, ew, cursor, edata);

    dim3 grid_mlp((N_NODES + 63) / 64, 4);
    mlp_all_kernel<<<grid_mlp, 256, 0, stream>>>(emb, pw, cbias, flags, h, acc);

    gather_kernel<<<(N_NODES + 3) / 4, 256, 0, stream>>>(
        offsets, edata, h, ccoef, acc, d_out, flags);
}

// Round 5
// 294.026 us; speedup vs baseline: 4.1010x; 1.2089x over previous
//
#include <hip/hip_runtime.h>

#define N_NODES 50000
#define N_EDGES 600000
#define C 128
#define STRIPS 3125          // N_NODES / 16
#define N_TASKS 3            // 0: rel+loop (layer2), 1: hh0 (layer1), 2: hh1 (layer0)

typedef __bf16 bf16;
typedef __attribute__((ext_vector_type(8))) __bf16 bf16x8;
typedef __attribute__((ext_vector_type(4))) __bf16 bf16x4;
typedef __attribute__((ext_vector_type(2))) __bf16 bf16x2;
typedef __attribute__((ext_vector_type(4))) float f32x4;
typedef __attribute__((ext_vector_type(2))) float f32x2;

struct PtrsV { const void* p[8]; };

// ---------------------------------------------------------------------------
// Dtype detection (verified R2/R3): flags 1 = fp32, 0 = bf16.
// ---------------------------------------------------------------------------
__device__ __forceinline__ int bf16_wild(unsigned short w) {
    int exp = (w >> 7) & 0xFF;
    int mant = w & 0x7F;
    if (exp == 0xFF) return 1;
    if (exp >= 133) return 1;                // |x| >= 64
    if (exp == 0) return mant != 0 ? 1 : 0;  // denormal
    if (exp <= 114) return 1;                // 0 < |x| < 2^-12
    return 0;
}

__global__ void __launch_bounds__(64) detect_kernel(
    const unsigned short* __restrict__ emb,
    const unsigned short* __restrict__ w,
    const unsigned short* __restrict__ b,
    const unsigned short* __restrict__ hc,
    int* __restrict__ flags)
{
    int lane = threadIdx.x;
    int ce = 0, cw = 0, cb = 0, ch = 0;
    for (int j = 0; j < 4; ++j) {
        ce += bf16_wild(emb[lane * 4 + j]);
        cw += bf16_wild(w[lane * 4 + j]);
    }
    for (int j = 0; j < 2; ++j) cb += bf16_wild(b[lane * 2 + j]);
    if (lane < 3) ch = bf16_wild(hc[lane]);
    for (int off = 32; off > 0; off >>= 1) {
        ce += __shfl_down(ce, off);
        cw += __shfl_down(cw, off);
        cb += __shfl_down(cb, off);
        ch += __shfl_down(ch, off);
    }
    if (lane == 0) {
        int wf = (cw >= 16) ? 1 : 0;
        flags[0] = (ce >= 16) ? 1 : 0;
        flags[1] = wf;
        flags[2] = (cb >= 8) ? 1 : 0;
        flags[3] = (ch > 0) ? 1 : wf;
    }
}

// ---------------------------------------------------------------------------
// Pack weights into MFMA B-fragment order (verified R2/R3).
// Slots 4,5 are the second hh matrix (+16384 elems / +128 bias).
// ---------------------------------------------------------------------------
__global__ void __launch_bounds__(256) pack_kernel(
    PtrsV wmats, PtrsV bvecs, const void* hc_raw,
    const int* __restrict__ flags,
    bf16* __restrict__ pw, float* __restrict__ cbias, float* __restrict__ ccoef)
{
    int tid = blockIdx.x * 256 + threadIdx.x;
    int wf = flags[1], bfl = flags[2], hf = flags[3];
    if (tid < 8 * 16384) {
        int m    = tid >> 14;
        int r    = tid & 16383;
        int j    = r & 7;
        int lane = (r >> 3) & 63;
        int n0   = (r >> 9) & 7;
        int kk   = r >> 12;
        int k = kk * 32 + (lane >> 4) * 8 + j;
        int n = n0 * 16 + (lane & 15);
        int idx = k * C + n + ((m == 4 || m == 5) ? 16384 : 0);
        float v = wf ? ((const float*)wmats.p[m])[idx]
                     : (float)((const bf16*)wmats.p[m])[idx];
        pw[tid] = (bf16)v;
    } else if (tid < 8 * 16384 + 1024) {
        int j = tid - 8 * 16384;
        int m = j >> 7, n = j & 127;
        int idx = n + ((m == 4 || m == 5) ? 128 : 0);
        float v = bfl ? ((const float*)bvecs.p[m])[idx]
                      : (float)((const bf16*)bvecs.p[m])[idx];
        cbias[j] = v;
    } else if (tid < 8 * 16384 + 1024 + 3) {
        int i = tid - (8 * 16384 + 1024);
        float v = hf ? ((const float*)hc_raw)[i]
                     : (float)((const bf16*)hc_raw)[i];
        ccoef[i] = v;
    }
}

// ---------------------------------------------------------------------------
// MLP v2 helpers. Per-wave 16-node strip, no barriers.
// A layout: A[m=lane&15][k=quad*8+j]; B frag from pw; C/D: col=lane&15,
// row=quad*4+reg (all verified in R2/R3 kernels).
// ---------------------------------------------------------------------------
__device__ __forceinline__ void run_mlp(
    const bf16x8 af[4], const bf16* __restrict__ w1, const bf16* __restrict__ w2,
    const float* __restrict__ b1, const float* __restrict__ b2,
    float oscale, bf16 (*sh)[136], int lrow, int lquad)
{
    // GEMM1: hidden = relu(X @ W1 + b1) -> sh
    #pragma unroll
    for (int n0 = 0; n0 < 8; ++n0) {
        const bf16x8* bp = (const bf16x8*)w1 + n0 * 64 + (lquad * 16 + lrow);
        bf16x8 bv0 = bp[0];
        bf16x8 bv1 = bp[512];
        bf16x8 bv2 = bp[1024];
        bf16x8 bv3 = bp[1536];
        f32x4 a4 = {0.f, 0.f, 0.f, 0.f};
        a4 = __builtin_amdgcn_mfma_f32_16x16x32_bf16(af[0], bv0, a4, 0, 0, 0);
        a4 = __builtin_amdgcn_mfma_f32_16x16x32_bf16(af[1], bv1, a4, 0, 0, 0);
        a4 = __builtin_amdgcn_mfma_f32_16x16x32_bf16(af[2], bv2, a4, 0, 0, 0);
        a4 = __builtin_amdgcn_mfma_f32_16x16x32_bf16(af[3], bv3, a4, 0, 0, 0);
        int n = n0 * 16 + lrow;
        float bias = b1[n];
        #pragma unroll
        for (int r = 0; r < 4; ++r) {
            float v = a4[r] + bias;
            v = v > 0.f ? v : 0.f;
            sh[lquad * 4 + r][n] = (bf16)v;
        }
    }
    // GEMM2 A-frags from sh (within-wave cross-lane; compiler inserts lgkmcnt)
    bf16x8 ah[4];
    #pragma unroll
    for (int kk = 0; kk < 4; ++kk)
        ah[kk] = *(const bf16x8*)(&sh[lrow][kk * 32 + lquad * 8]);
    // GEMM2: out = oscale * (hidden @ W2 + b2) -> sh (overwrite)
    #pragma unroll
    for (int n0 = 0; n0 < 8; ++n0) {
        const bf16x8* bp = (const bf16x8*)w2 + n0 * 64 + (lquad * 16 + lrow);
        bf16x8 bv0 = bp[0];
        bf16x8 bv1 = bp[512];
        bf16x8 bv2 = bp[1024];
        bf16x8 bv3 = bp[1536];
        f32x4 a4 = {0.f, 0.f, 0.f, 0.f};
        a4 = __builtin_amdgcn_mfma_f32_16x16x32_bf16(ah[0], bv0, a4, 0, 0, 0);
        a4 = __builtin_amdgcn_mfma_f32_16x16x32_bf16(ah[1], bv1, a4, 0, 0, 0);
        a4 = __builtin_amdgcn_mfma_f32_16x16x32_bf16(ah[2], bv2, a4, 0, 0, 0);
        a4 = __builtin_amdgcn_mfma_f32_16x16x32_bf16(ah[3], bv3, a4, 0, 0, 0);
        int n = n0 * 16 + lrow;
        float bias = b2[n];
        #pragma unroll
        for (int r = 0; r < 4; ++r)
            sh[lquad * 4 + r][n] = (bf16)((a4[r] + bias) * oscale);
    }
}

__device__ __forceinline__ void store_strip(
    const bf16 (*sh)[136], bf16* __restrict__ dst, int lane)
{
    int row = lane >> 2;             // 0..15
    int cs  = (lane & 3) * 32;       // 0,32,64,96
    #pragma unroll
    for (int i = 0; i < 4; ++i) {
        bf16x8 v = *(const bf16x8*)(&sh[row][cs + i * 8]);
        *(bf16x8*)(dst + (size_t)row * C + cs + i * 8) = v;
    }
}

// grid: ceil(3*STRIPS/4) blocks x 256. Wave w handles (task, strip).
__global__ __launch_bounds__(256, 4) void mlp_kernel(
    const void* __restrict__ emb_raw,    // [3][N][C] fp32 or bf16
    const bf16* __restrict__ pw,         // packed weights [8][16384]
    const float* __restrict__ cbias,     // [8][128]
    const float* __restrict__ ccoef,     // [3]
    const int* __restrict__ flags,
    bf16* __restrict__ h,                // [3][N][C], premultiplied by coef
    bf16* __restrict__ hs)               // [N][C] self term
{
    __shared__ bf16 sH[4][16][136];
    const int tid  = threadIdx.x;
    const int wave = tid >> 6, lane = tid & 63;
    const int wid  = blockIdx.x * 4 + wave;
    if (wid >= N_TASKS * STRIPS) return;
    const int task  = wid / STRIPS;
    const int strip = wid - task * STRIPS;
    const int node0 = strip * 16;
    const int lrow = lane & 15, lquad = lane >> 4;
    bf16 (*sh)[136] = sH[wave];

    // ---- X a-fragments direct from global (layer = 2 - task) ----
    const size_t xbase = (size_t)(2 - task) * N_NODES * C
                       + (size_t)(node0 + lrow) * C + lquad * 8;
    bf16x8 af[4];
    if (flags[0]) {
        const float* xf = (const float*)emb_raw + xbase;
        #pragma unroll
        for (int kk = 0; kk < 4; ++kk) {
            f32x4 u0 = *(const f32x4*)(xf + kk * 32);
            f32x4 u1 = *(const f32x4*)(xf + kk * 32 + 4);
            bf16x8 v;
            v[0] = (bf16)u0[0]; v[1] = (bf16)u0[1]; v[2] = (bf16)u0[2]; v[3] = (bf16)u0[3];
            v[4] = (bf16)u1[0]; v[5] = (bf16)u1[1]; v[6] = (bf16)u1[2]; v[7] = (bf16)u1[3];
            af[kk] = v;
        }
    } else {
        const bf16* xb = (const bf16*)emb_raw + xbase;
        #pragma unroll
        for (int kk = 0; kk < 4; ++kk)
            af[kk] = *(const bf16x8*)(xb + kk * 32);
    }

    if (task == 0) {
        // rel MLP -> h[0] (scaled by coef0)
        run_mlp(af, pw, pw + 16384, cbias, cbias + 128, ccoef[0], sh, lrow, lquad);
        store_strip(sh, h + (size_t)node0 * C, lane);
        // loop MLP (self term) -> hs (scale 1); af still live in registers
        run_mlp(af, pw + 6 * 16384, pw + 7 * 16384, cbias + 6 * 128, cbias + 7 * 128,
                1.0f, sh, lrow, lquad);
        store_strip(sh, hs + (size_t)node0 * C, lane);
    } else if (task == 1) {
        run_mlp(af, pw + 2 * 16384, pw + 3 * 16384, cbias + 2 * 128, cbias + 3 * 128,
                ccoef[1], sh, lrow, lquad);
        store_strip(sh, h + (size_t)N_NODES * C + (size_t)node0 * C, lane);
    } else {
        run_mlp(af, pw + 4 * 16384, pw + 5 * 16384, cbias + 4 * 128, cbias + 5 * 128,
                ccoef[2], sh, lrow, lquad);
        store_strip(sh, h + (size_t)2 * N_NODES * C + (size_t)node0 * C, lane);
    }
}

// ---------------------------------------------------------------------------
// CSR build: histogram, 3-phase scan, bucket fill.
// ---------------------------------------------------------------------------
__global__ void __launch_bounds__(256) hist_kernel(
    const int* __restrict__ erow, int* __restrict__ deg)
{
    int e = blockIdx.x * 256 + threadIdx.x;
    if (e >= N_EDGES) return;
    atomicAdd(&deg[erow[e]], 1);
}

__device__ __forceinline__ int wave_incl_scan(int v, int lane) {
    int x = v;
    #pragma unroll
    for (int d = 1; d < 64; d <<= 1) {
        int t = __shfl_up(x, d);
        if (lane >= d) x += t;
    }
    return x;
}

// Phase A: per-block (256-elem) exclusive scan -> offsets (local), btot[block]
__global__ void __launch_bounds__(256) scanA_kernel(
    const int* __restrict__ deg, int* __restrict__ offsets, int* __restrict__ btot)
{
    __shared__ int swave[4];
    int b = blockIdx.x, tid = threadIdx.x;
    int i = b * 256 + tid;
    int lane = tid & 63, wv = tid >> 6;
    int v = (i < N_NODES) ? deg[i] : 0;
    int x = wave_incl_scan(v, lane);
    if (lane == 63) swave[wv] = x;
    __syncthreads();
    int w0 = swave[0], w1 = swave[1], w2 = swave[2], w3 = swave[3];
    int wp = (wv > 0 ? w0 : 0) + (wv > 1 ? w1 : 0) + (wv > 2 ? w2 : 0);
    if (i < N_NODES) offsets[i] = wp + x - v;
    if (tid == 0) btot[b] = w0 + w1 + w2 + w3;
}

// Phase B: exclusive scan of 196 block totals -> bbase
__global__ void __launch_bounds__(256) scanB_kernel(
    const int* __restrict__ btot, int* __restrict__ bbase, int nblk)
{
    __shared__ int swave[4];
    int tid = threadIdx.x;
    int lane = tid & 63, wv = tid >> 6;
    int v = (tid < nblk) ? btot[tid] : 0;
    int x = wave_incl_scan(v, lane);
    if (lane == 63) swave[wv] = x;
    __syncthreads();
    int w0 = swave[0], w1 = swave[1], w2 = swave[2], w3 = swave[3];
    int wp = (wv > 0 ? w0 : 0) + (wv > 1 ? w1 : 0) + (wv > 2 ? w2 : 0);
    if (tid < nblk) bbase[tid] = wp + x - v;
}

// Phase C: add block bases; init cursor; offsets[N] = E
__global__ void __launch_bounds__(256) scanC_kernel(
    const int* __restrict__ bbase, int* __restrict__ offsets, int* __restrict__ cursor)
{
    int i = blockIdx.x * 256 + threadIdx.x;
    if (i < N_NODES) {
        int o = offsets[i] + bbase[blockIdx.x];
        offsets[i] = o;
        cursor[i] = o;
    }
    if (i == 0) offsets[N_NODES] = N_EDGES;
}

__global__ void __launch_bounds__(256) fill_kernel(
    const int* __restrict__ erow, const int* __restrict__ ecol,
    const int* __restrict__ ew,
    int* __restrict__ cursor, int* __restrict__ edata)
{
    int e = blockIdx.x * 256 + threadIdx.x;
    if (e >= N_EDGES) return;
    int dst = erow[e];
    int pos = atomicAdd(&cursor[dst], 1);
    edata[pos] = (ecol[e] << 2) | (ew[e] - 1);
}

// ---------------------------------------------------------------------------
// Gather: one wave per node, lane = 2 channels. h is coef-premultiplied, so
// the inner op is a plain add. 4x unroll -> 4 loads in flight.
// ---------------------------------------------------------------------------
__global__ void __launch_bounds__(256) gather_kernel(
    const int* __restrict__ offsets, const int* __restrict__ edata,
    const bf16* __restrict__ h,          // [3][N][C]
    const bf16* __restrict__ hs,         // [N][C]
    void* __restrict__ out,
    const int* __restrict__ flags)
{
    const int node = blockIdx.x * 4 + (threadIdx.x >> 6);
    if (node >= N_NODES) return;
    const int lane = threadIdx.x & 63;
    const int c = lane * 2;

    bf16x2 sv = *(const bf16x2*)(hs + (size_t)node * C + c);
    float a0 = (float)sv[0], a1 = (float)sv[1];

    const int s = offsets[node], e = offsets[node + 1];
    for (int base = s; base < e; base += 64) {
        int idx = base + lane;
        int ed_i = (idx < e) ? edata[idx] : 0;
        int cnt = e - base; if (cnt > 64) cnt = 64;
        int j = 0;
        for (; j + 4 <= cnt; j += 4) {
            int e0 = __shfl(ed_i, j);
            int e1 = __shfl(ed_i, j + 1);
            int e2 = __shfl(ed_i, j + 2);
            int e3 = __shfl(ed_i, j + 3);
            bf16x2 v0 = *(const bf16x2*)(h + (size_t)(e0 & 3) * (N_NODES * C) + (size_t)(e0 >> 2) * C + c);
            bf16x2 v1 = *(const bf16x2*)(h + (size_t)(e1 & 3) * (N_NODES * C) + (size_t)(e1 >> 2) * C + c);
            bf16x2 v2 = *(const bf16x2*)(h + (size_t)(e2 & 3) * (N_NODES * C) + (size_t)(e2 >> 2) * C + c);
            bf16x2 v3 = *(const bf16x2*)(h + (size_t)(e3 & 3) * (N_NODES * C) + (size_t)(e3 >> 2) * C + c);
            a0 += (float)v0[0] + (float)v1[0] + (float)v2[0] + (float)v3[0];
            a1 += (float)v0[1] + (float)v1[1] + (float)v2[1] + (float)v3[1];
        }
        for (; j < cnt; ++j) {
            int ed = __shfl(ed_i, j);
            bf16x2 v = *(const bf16x2*)(h + (size_t)(ed & 3) * (N_NODES * C) + (size_t)(ed >> 2) * C + c);
            a0 += (float)v[0];
            a1 += (float)v[1];
        }
    }

    if (flags[0]) {
        f32x2 o; o[0] = a0; o[1] = a1;
        *(f32x2*)((float*)out + (size_t)node * C + c) = o;
    } else {
        bf16x2 o; o[0] = (bf16)a0; o[1] = (bf16)a1;
        *(bf16x2*)((bf16*)out + (size_t)node * C + c) = o;
    }
}

// ---------------------------------------------------------------------------
extern "C" void kernel_launch(void* const* d_in, const int* in_sizes, int n_in,
                              void* d_out, int out_size, void* d_ws, size_t ws_size,
                              hipStream_t stream) {
    // 0 t | 1 node_embeddings [3,N,C] | 2 edge_index [2,E] | 3 edge_weights [E]
    // 4 loop_W1 5 loop_b1 6 loop_W2 7 loop_b2 | 8 rel_W1 9 rel_b1 10 rel_W2 11 rel_b2
    // 12 hh_W1 [2,C,C] 13 hh_b1 [2,C] 14 hh_W2 [2,C,C] 15 hh_b2 [2,C] | 16 hop_coef [3]
    const void* emb = d_in[1];
    const int*  ei  = (const int*)d_in[2];
    const int*  ew  = (const int*)d_in[3];

    // ws layout
    const size_t H_BYTES  = (size_t)3 * N_NODES * C * sizeof(bf16);   // 38.4 MB
    const size_t HS_BYTES = (size_t)N_NODES * C * sizeof(bf16);       // 12.8 MB
    const size_t PW_BYTES = (size_t)8 * 16384 * sizeof(bf16);         // 256 KB
    bf16*  h      = (bf16*)d_ws;
    bf16*  hs     = (bf16*)((char*)d_ws + H_BYTES);
    bf16*  pw     = (bf16*)((char*)d_ws + H_BYTES + HS_BYTES);
    float* cbias  = (float*)((char*)d_ws + H_BYTES + HS_BYTES + PW_BYTES);
    float* ccoef  = cbias + 1024;
    int*   flags  = (int*)(ccoef + 4);
    int*   deg    = flags + 16;
    int*   cursor = deg + N_NODES;
    int*   offsets= cursor + N_NODES;
    int*   btot   = offsets + N_NODES + 8;
    int*   bbase  = btot + 256;
    int*   edata  = bbase + 256;

    // MLP id -> matrices: 0:rel  1:hh[0]  2:hh[1]  3:loop
    PtrsV wptr;
    wptr.p[0] = d_in[8];   wptr.p[1] = d_in[10];
    wptr.p[2] = d_in[12];  wptr.p[3] = d_in[14];
    wptr.p[4] = d_in[12];  wptr.p[5] = d_in[14];   // +16384 elems inside pack
    wptr.p[6] = d_in[4];   wptr.p[7] = d_in[6];
    PtrsV bptr;
    bptr.p[0] = d_in[9];   bptr.p[1] = d_in[11];
    bptr.p[2] = d_in[13];  bptr.p[3] = d_in[15];
    bptr.p[4] = d_in[13];  bptr.p[5] = d_in[15];   // +128 inside pack
    bptr.p[6] = d_in[5];   bptr.p[7] = d_in[7];

    detect_kernel<<<1, 64, 0, stream>>>(
        (const unsigned short*)emb, (const unsigned short*)d_in[8],
        (const unsigned short*)d_in[9], (const unsigned short*)d_in[16], flags);

    pack_kernel<<<517, 256, 0, stream>>>(wptr, bptr, d_in[16], flags, pw, cbias, ccoef);

    // CSR build
    hipMemsetAsync(deg, 0, N_NODES * sizeof(int), stream);
    const int* erow = ei;
    const int* ecol = ei + N_EDGES;
    const int NBLK = (N_NODES + 255) / 256;   // 196
    hist_kernel<<<(N_EDGES + 255) / 256, 256, 0, stream>>>(erow, deg);
    scanA_kernel<<<NBLK, 256, 0, stream>>>(deg, offsets, btot);
    scanB_kernel<<<1, 256, 0, stream>>>(btot, bbase, NBLK);
    scanC_kernel<<<NBLK, 256, 0, stream>>>(bbase, offsets, cursor);
    fill_kernel<<<(N_EDGES + 255) / 256, 256, 0, stream>>>(erow, ecol, ew, cursor, edata);

    // MLPs (barrier-free, per-wave strips)
    const int n_waves = N_TASKS * STRIPS;                 // 9375
    mlp_kernel<<<(n_waves + 3) / 4, 256, 0, stream>>>(emb, pw, cbias, ccoef, flags, h, hs);

    gather_kernel<<<(N_NODES + 3) / 4, 256, 0, stream>>>(
        offsets, edata, h, hs, d_out, flags);
}